// Round 5
// baseline (387.326 us; speedup 1.0000x reference)
//
#include <hip/hip_runtime.h>
#include <math.h>

#define NPTS  65536
#define KNN   10
#define PK    25
#define NCOUT 64
#define GRIDB 10          // pooling grid (cell 0.1) — must match reference
#define NSEG  1000
#define GRIDC 20          // kNN search grid (cell 0.05)
#define NCELL (GRIDC*GRIDC*GRIDC)
#define CELLK 0.05f
#define R0SQ  0.002025f   // 0.045^2 collect radius: E[in-ball]=25.0, P(<10)=3e-4, P(>48)=3e-4
#define SLAB_CAP 832      // union slab: mean 664, sigma 26 (+6 sigma)
#define LIST_CAP 48
#define LIST_STRIDE 50    // u16 stride 100B -> 2 lanes/bank (free)

// ---- workspace layout (bytes) ----
#define OFF_SORTED  0           // float4 sorted[65536]
#define OFF_HIST    1048576     // int hist[8000]
#define OFF_CSTART  1080576     // int cstart[8001]
#define OFF_CURSOR  1112580     // int cursor[8000]
#define OFF_POOL    1144592     // float: counts[1000] | spt[1000*3] | sinf[1000*25]
#define MEMSET_SIZE (32000 + 32004 + 32000 + 116000 + 12)  // hist..pool contiguous

__device__ __forceinline__ int cell_of(float px, float py, float pz) {
    int gx = min((int)(px * (float)GRIDC), GRIDC - 1);
    int gy = min((int)(py * (float)GRIDC), GRIDC - 1);
    int gz = min((int)(pz * (float)GRIDC), GRIDC - 1);
    return (gx * GRIDC + gy) * GRIDC + gz;
}

__global__ __launch_bounds__(256) void hist_kernel(
    const float* __restrict__ pts, int* __restrict__ hist)
{
    int g = blockIdx.x * 256 + threadIdx.x;
    float px = pts[g*3+0], py = pts[g*3+1], pz = pts[g*3+2];
    atomicAdd(&hist[cell_of(px, py, pz)], 1);
}

__global__ __launch_bounds__(256) void scan_kernel(
    const int* __restrict__ hist, int* __restrict__ cstart, int* __restrict__ cursor)
{
    __shared__ int part[256];
    const int t = threadIdx.x;
    const int base = t * 32;                       // 256*32 = 8192 >= 8000
    int s = 0;
    for (int i = 0; i < 32; ++i) {
        int c = base + i;
        s += (c < NCELL) ? hist[c] : 0;
    }
    part[t] = s;
    __syncthreads();
    for (int off = 1; off < 256; off <<= 1) {
        int v = (t >= off) ? part[t - off] : 0;
        __syncthreads();
        part[t] += v;
        __syncthreads();
    }
    int run = (t == 0) ? 0 : part[t - 1];
    for (int i = 0; i < 32; ++i) {
        int c = base + i;
        if (c < NCELL) {
            cstart[c] = run;
            cursor[c] = run;
            run += hist[c];
        }
    }
    if (t == 255) cstart[NCELL] = run;
}

__global__ __launch_bounds__(256) void scatter_kernel(
    const float* __restrict__ pts, int* __restrict__ cursor, float4* __restrict__ sorted)
{
    int g = blockIdx.x * 256 + threadIdx.x;
    float px = pts[g*3+0], py = pts[g*3+1], pz = pts[g*3+2];
    int c = cell_of(px, py, pz);
    int pos = atomicAdd(&cursor[c], 1);
    sorted[pos] = make_float4(px, py, pz, 0.f);
}

__device__ __forceinline__ void insert10(float (&kd)[KNN], int (&ki)[KNN],
                                         float d, int idx)
{
    float cd = d; int ci = idx;
#pragma unroll
    for (int u = 0; u < KNN; ++u) {
        bool lt = cd < kd[u];                  // strict: stable (earlier wins ties)
        float td = kd[u]; int ti = ki[u];
        kd[u] = lt ? cd : kd[u];
        ki[u] = lt ? ci : ki[u];
        cd = lt ? td : cd;
        ci = lt ? ti : ci;
    }
}

// One wave (64 lanes) per z-column segment; lane = one query.
// blocks = 400 columns x 3 segments.
__global__ __launch_bounds__(64) void knn_kpconv_pool(
    const float4* __restrict__ sorted,
    const int*    __restrict__ cstart,
    const float*  __restrict__ kern,
    float*        __restrict__ pool)
{
    __shared__ float4 cand[SLAB_CAP];                 // 13312 B
    __shared__ unsigned short lst[64 * LIST_STRIDE];  // 6400 B
    __shared__ float4 kpt[PK];                        // 400 B

    const int tid = threadIdx.x;
    const int col = blockIdx.x / 3;
    const int seg = blockIdx.x % 3;
    const int cx = col / GRIDC, cy = col % GRIDC;
    const int cz0 = (seg < 2) ? seg * 7 : 14;
    const int len = (seg < 2) ? 7 : 6;
    const int colBase = col * GRIDC;

    const int qb = cstart[colBase + cz0];
    const int qe = cstart[colBase + cz0 + len];
    const int qn = qe - qb;
    if (qn == 0) return;

    if (tid < PK)
        kpt[tid] = make_float4(kern[tid*3+0], kern[tid*3+1], kern[tid*3+2], 0.f);

    const int zA = max(cz0 - 1, 0);
    const int zB = min(cz0 + len, GRIDC - 1);

    // ---- chunk table: 3x3 neighbor columns, ascending (x,y) = ascending cell id
    int cB[9], cS[9], cL[9], cCol[9];
    int ncand = 0;
#pragma unroll
    for (int a = 0; a < 3; ++a)
#pragma unroll
        for (int b = 0; b < 3; ++b) {
            int c = a * 3 + b;
            int xx = cx - 1 + a, yy = cy - 1 + b;
            bool v = ((unsigned)xx < GRIDC) && ((unsigned)yy < GRIDC);
            int cc = v ? (xx * GRIDC + yy) * GRIDC : 0;
            int s0 = v ? cstart[cc + zA] : 0;
            int e0 = v ? cstart[cc + zB + 1] : 0;
            cCol[c] = cc; cS[c] = s0; cB[c] = ncand; cL[c] = e0 - s0;
            ncand += e0 - s0;
        }
    const bool slabOvf = (ncand > SLAB_CAP);

    // ---- stage slab (coalesced, |s|^2 in .w)
#pragma unroll
    for (int c = 0; c < 9; ++c) {
        int lim = min(cL[c], SLAB_CAP - cB[c]);
        for (int i = tid; i < lim; i += 64) {
            float4 p = sorted[cS[c] + i];
            p.w = p.x*p.x + p.y*p.y + p.z*p.z;
            cand[cB[c] + i] = p;
        }
    }
    __syncthreads();

    const float inv_sigma = 1.0f / (2.1f * 0.05f);
    float* counts = pool;
    float* spt    = pool + NSEG;
    float* sinf   = pool + NSEG * 4;

    for (int qbase = 0; qbase < qn; qbase += 64) {
        const bool active = (qbase + tid) < qn;
        const int qidx = qb + qbase + (active ? tid : 0);
        const float4 Q = sorted[qidx];
        const float qq  = Q.x*Q.x + Q.y*Q.y + Q.z*Q.z;
        const float m2x = -2.f*Q.x, m2y = -2.f*Q.y, m2z = -2.f*Q.z;
        const int czl = min((int)(Q.z * (float)GRIDC), GRIDC - 1);
        const int zlo = max(czl - 1, 0), zhi = min(czl + 1, GRIDC - 1);

        // per-lane window inside each chunk (its own cell's ring-1 z-range)
        int wlo[9], whi[9];
#pragma unroll
        for (int c = 0; c < 9; ++c) {
            if (cL[c] > 0) {
                int lo = cB[c] + (cstart[cCol[c] + zlo]     - cS[c]);
                int hi = cB[c] + (cstart[cCol[c] + zhi + 1] - cS[c]);
                wlo[c] = min(lo, SLAB_CAP); whi[c] = min(hi, SLAB_CAP);
            } else { wlo[c] = 0; whi[c] = 0; }
        }

        // ---- collect: append candidates with d < r0^2 to per-lane u16 list
        int cnt = 0; bool ovf = false;
        const int lb = tid * LIST_STRIDE;
#pragma unroll
        for (int c = 0; c < 9; ++c) {
            for (int j = wlo[c]; j < whi[c]; ++j) {
                float4 s = cand[j];
                float t = fmaf(m2x, s.x, s.w);
                t = fmaf(m2y, s.y, t);
                t = fmaf(m2z, s.z, t);
                float d = t + qq;
                if (d < R0SQ) {
                    if (cnt < LIST_CAP) { lst[lb + cnt] = (unsigned short)j; ++cnt; }
                    else ovf = true;
                }
            }
        }

        // ---- select: per-lane top-10 over its ~25-entry list
        float kd[KNN]; int ki[KNN];
#pragma unroll
        for (int u = 0; u < KNN; ++u) { kd[u] = 3.4e38f; ki[u] = -1; }
        for (int i = 0; i < cnt; ++i) {
            int j = lst[lb + i];
            float4 s = cand[j];
            float t = fmaf(m2x, s.x, s.w);
            t = fmaf(m2y, s.y, t);
            t = fmaf(m2z, s.z, t);
            float d = t + qq;
            if (d < kd[KNN-1]) insert10(kd, ki, d, j);
        }
        const bool resolved = active && !slabOvf && !ovf && (cnt >= KNN);

        // ---- tier-1: unbounded rescan of own window (exact iff d10 <= 0.05)
        const bool needT1 = active && !resolved && !slabOvf;
        if (__any(needT1)) {
            if (needT1) {
#pragma unroll
                for (int u = 0; u < KNN; ++u) { kd[u] = 3.4e38f; ki[u] = -1; }
#pragma unroll
                for (int c = 0; c < 9; ++c) {
                    for (int j = wlo[c]; j < whi[c]; ++j) {
                        float4 s = cand[j];
                        float t = fmaf(m2x, s.x, s.w);
                        t = fmaf(m2y, s.y, t);
                        t = fmaf(m2z, s.z, t);
                        float d = t + qq;
                        if (d < kd[KNN-1]) insert10(kd, ki, d, j);
                    }
                }
            }
        }
        const bool fbG = active &&
            ((needT1 && kd[KNN-1] > CELLK*CELLK) || slabOvf);

        // ---- tier-2: rare per-lane exact global ring walk
        if (__any(fbG)) {
            if (fbG) {
#pragma unroll
                for (int u = 0; u < KNN; ++u) { kd[u] = 3.4e38f; ki[u] = -1; }
                auto scanColG = [&](int x, int y, int z0, int z1) {
                    if ((unsigned)x >= GRIDC || (unsigned)y >= GRIDC) return;
                    z0 = max(z0, 0); z1 = min(z1, GRIDC - 1);
                    if (z0 > z1) return;
                    int cc = (x * GRIDC + y) * GRIDC;
                    int b0 = cstart[cc + z0], e0 = cstart[cc + z1 + 1];
                    for (int j = b0; j < e0; ++j) {
                        float4 s = sorted[j];
                        float dx = Q.x - s.x, dy = Q.y - s.y, dz = Q.z - s.z;
                        float d = dx * dx;
                        d = fmaf(dy, dy, d);
                        d = fmaf(dz, dz, d);
                        if (d < kd[KNN-1]) insert10(kd, ki, d, j);
                    }
                };
                for (int xx = cx-1; xx <= cx+1; ++xx)
                    for (int yy = cy-1; yy <= cy+1; ++yy)
                        scanColG(xx, yy, czl-1, czl+1);
                int r = 1;
                while (r < GRIDC && kd[KNN-1] > (r*CELLK)*(r*CELLK)) {
                    ++r;
                    for (int xx = cx-r; xx <= cx+r; ++xx)
                        for (int yy = cy-r; yy <= cy+r; ++yy) {
                            int ch = max(abs(xx-cx), abs(yy-cy));
                            if (ch == r) scanColG(xx, yy, czl-r, czl+r);
                            else { scanColG(xx, yy, czl-r, czl-r);
                                   scanColG(xx, yy, czl+r, czl+r); }
                        }
                }
            }
        }

        // ---- influence + pooling (per-lane, fully parallel)
        if (active) {
            float acc[PK];
#pragma unroll
            for (int p = 0; p < PK; ++p) acc[p] = 0.f;

#pragma unroll
            for (int u = 0; u < KNN; ++u) {
                int j = ki[u];
                if (j >= 0) {
                    float4 nb;
                    if (fbG) nb = sorted[j]; else nb = cand[j];
                    float rx = nb.x - Q.x, ry = nb.y - Q.y, rz = nb.z - Q.z;
#pragma unroll
                    for (int p = 0; p < PK; ++p) {
                        float ddx = rx - kpt[p].x, ddy = ry - kpt[p].y, ddz = rz - kpt[p].z;
                        float d2 = ddx * ddx;
                        d2 = fmaf(ddy, ddy, d2);
                        d2 = fmaf(ddz, ddz, d2);
                        acc[p] += fmaxf(0.f, fmaf(-inv_sigma, sqrtf(d2), 1.f));
                    }
                }
            }

            int gx = min(max((int)floorf(Q.x / 0.1f), 0), GRIDB - 1);
            int gy = min(max((int)floorf(Q.y / 0.1f), 0), GRIDB - 1);
            int gz = min(max((int)floorf(Q.z / 0.1f), 0), GRIDB - 1);
            const int sg = (gx * GRIDB + gy) * GRIDB + gz;
            atomicAdd(&counts[sg], 1.0f);
            atomicAdd(&spt[sg*3+0], Q.x);
            atomicAdd(&spt[sg*3+1], Q.y);
            atomicAdd(&spt[sg*3+2], Q.z);
#pragma unroll
            for (int p = 0; p < PK; ++p) atomicAdd(&sinf[sg*PK + p], acc[p]);
        }
    }
}

__global__ __launch_bounds__(64) void finalize(
    const float* __restrict__ pool,
    const float* __restrict__ W,
    float* __restrict__ out)
{
    const int s = blockIdx.x;
    const int d = threadIdx.x;
    __shared__ float sInfl[PK];
    if (d < PK) sInfl[d] = pool[NSEG*4 + s*PK + d];
    __syncthreads();

    float c = fmaxf(pool[s], 1.0f);
    float inv = 1.0f / c;

    float a = 0.f;
#pragma unroll
    for (int p = 0; p < PK; ++p) a = fmaf(sInfl[p], W[p*NCOUT + d], a);
    out[NSEG*3 + s*NCOUT + d] = a * inv;

    if (d < 3) out[s*3 + d] = pool[NSEG + s*3 + d] * inv;
}

extern "C" void kernel_launch(void* const* d_in, const int* in_sizes, int n_in,
                              void* d_out, int out_size, void* d_ws, size_t ws_size,
                              hipStream_t stream)
{
    const float* pts  = (const float*)d_in[0];
    const float* kern = (const float*)d_in[1];
    const float* W    = (const float*)d_in[2];
    float* out = (float*)d_out;
    char*  ws  = (char*)d_ws;

    float4* sorted = (float4*)(ws + OFF_SORTED);
    int*    hist   = (int*)   (ws + OFF_HIST);
    int*    cstart = (int*)   (ws + OFF_CSTART);
    int*    cursor = (int*)   (ws + OFF_CURSOR);
    float*  pool   = (float*) (ws + OFF_POOL);

    hipMemsetAsync(hist, 0, MEMSET_SIZE, stream);   // hist+cstart+cursor+pool contiguous

    hist_kernel    <<<NPTS/256, 256, 0, stream>>>(pts, hist);
    scan_kernel    <<<1,        256, 0, stream>>>(hist, cstart, cursor);
    scatter_kernel <<<NPTS/256, 256, 0, stream>>>(pts, cursor, sorted);
    knn_kpconv_pool<<<400*3,     64, 0, stream>>>(sorted, cstart, kern, pool);
    finalize       <<<NSEG,      64, 0, stream>>>(pool, W, out);
}